// Round 1
// baseline (670.344 us; speedup 1.0000x reference)
//
#include <hip/hip_runtime.h>

// OSQP batched ADMM, B=256 N=128 M=192, 400 iters.
// R6: loop_kernel redesigned row-per-lane. 256 thr/block; thread j<192 owns
// constraint-row j. V row (192 f32) resident in VGPRs as 96 v2f (1 wave/SIMD,
// 512-VGPR budget; LDS forces 1 block/CU anyway). s exchanged via PLAIN LDS
// s[j] (uniform broadcast ds_read_b128, no permutation). Removes red16 DPP
// reduce, lane select, isp divergence; barrier population 16 waves -> 4.
// Dot products via v_pk_fma_f32 (__builtin_elementwise_fma on v2f).
// WtT ([128][192], LDS stride 196) staged once: V-build reads rows broadcast;
// epilogue x_t = WtT[t][:].Sacc - c. Early BITWISE fixed-point exit every 8
// iters (exact: identity iterations skipped, Sacc settled analytically).
// precompute unchanged except Phase C stores Wt TRANSPOSED (coalesced in j).
// Algebra: M = P + sI + rho*AtA (SPD);  Wt = A*Minv;  c = Minv q
//   V = A Minv At;  d = A c
//   iterate (s_0=0), state (p, s, Sacc):
//     r = V s ; w = r - d ; v = a*w + p ; z = med3(v,l,u) ;
//     s' = rho*(2z - v) ; Sacc' = (1-a)Sacc + a*s ; p' = v - a*z
//   epilogue: x = Wt^T Sacc - c

#define Nn 128
#define Mm 192
constexpr float RHO_    = 0.1f;
constexpr float SIGMA_  = 1e-6f;
constexpr float ALPHA_  = 1.6f;
constexpr int   NITERS_ = 400;

typedef float v2f __attribute__((ext_vector_type(2)));
typedef float v4f __attribute__((ext_vector_type(4)));

//======================= Kernel 1: precompute WtT, c ===============================
// [R3-validated GJ core, unchanged]
template<int K0>
__device__ __forceinline__ void gj_block(float rr[32], float* __restrict__ buf0,
                                         float* __restrict__ buf1,
                                         const int irow, const int qq) {
  const bool qsel = (qq == K0);
  #pragma unroll
  for (int kk = 0; kk < 32; kk++) {
    const int k = 32*K0 + kk;
    float* wb = ((kk & 1) == 0) ? buf0 : buf1;
    if (irow == k) {
      #pragma unroll
      for (int j4 = 0; j4 < 8; j4++)
        *(float4*)&wb[36*qq + 4*j4] = *(const float4*)&rr[4*j4];
    }
    __syncthreads();
    const float akk  = wb[36*K0 + kk];
    float pinv = __builtin_amdgcn_rcpf(akk);
    pinv = pinv + pinv*(1.0f - akk*pinv);
    constexpr int QP = K0 | (K0<<2) | (K0<<4) | (K0<<6);
    const int fi = __builtin_amdgcn_update_dpp(__float_as_int(rr[kk]),
                      __float_as_int(rr[kk]), QP, 0xF, 0xF, false);
    const float f = __int_as_float(fi);
    const bool piv = (irow == k);
    float gfac = f * pinv;
    gfac = piv ? (1.0f - pinv) : gfac;
    float rk[32];
    #pragma unroll
    for (int j4 = 0; j4 < 8; j4++)
      *(float4*)&rk[4*j4] = *(const float4*)&wb[36*qq + 4*j4];
    #pragma unroll
    for (int j = 0; j < 32; j++) rr[j] -= gfac * rk[j];
    const float pivfix = piv ? pinv : -gfac;
    if (qsel) rr[kk] = pivfix;
  }
}

__global__ void __launch_bounds__(512, 2)
precompute_kernel(const float* __restrict__ Pg, const float* __restrict__ qg,
                  const float* __restrict__ Ag, float* __restrict__ wsWt,
                  float* __restrict__ wsC)
{
  __shared__ float smem[16384];
  const int t = threadIdx.x;
  const int b = blockIdx.x;
  const float* __restrict__ Pb = Pg + (size_t)b*Nn*Nn;
  const float* __restrict__ qb = qg + (size_t)b*Nn;
  const float* __restrict__ Ab = Ag + (size_t)b*Mm*Nn;

  //---- Phase A: S = P + sigma*I + rho * A^T A ----
  {
    const int ar = t & 31;
    const int bc = t >> 5;
    float acc[4][8];
    #pragma unroll
    for (int a=0;a<4;a++)
      #pragma unroll
      for (int j=0;j<8;j++) acc[a][j]=0.f;

    for (int c=0;c<6;c++) {
      __syncthreads();
      {
        const float4* src = (const float4*)(Ab + c*32*Nn);
        float4* dst = (float4*)smem;
        dst[t]     = src[t];
        dst[t+512] = src[t+512];
      }
      __syncthreads();
      #pragma unroll 2
      for (int m=0;m<32;m++) {
        const float4 ra  = *(const float4*)&smem[m*Nn + 4*ar];
        const float4 cb0 = *(const float4*)&smem[m*Nn + 8*bc];
        const float4 cb1 = *(const float4*)&smem[m*Nn + 8*bc + 4];
        const float rv[4] = {ra.x, ra.y, ra.z, ra.w};
        const float cv[8] = {cb0.x,cb0.y,cb0.z,cb0.w,cb1.x,cb1.y,cb1.z,cb1.w};
        #pragma unroll
        for (int a=0;a<4;a++)
          #pragma unroll
          for (int j=0;j<8;j++) acc[a][j] += rv[a]*cv[j];
      }
    }
    __syncthreads();
    #pragma unroll
    for (int a=0;a<4;a++) {
      const int i = 4*ar + a;
      #pragma unroll
      for (int j=0;j<8;j++) {
        const int jj = 8*bc + j;
        float v = Pb[i*Nn + jj] + RHO_*acc[a][j];
        if (i == jj) v += SIGMA_;
        smem[i*Nn + jj] = v;
      }
    }
    __syncthreads();
  }

  //---- Phase B: Gauss-Jordan inverse ----
  {
    const int irow = t >> 2;
    const int qq   = t & 3;
    float rr[32];
    #pragma unroll
    for (int j=0;j<32;j++) rr[j] = smem[irow*Nn + 32*qq + j];
    __syncthreads();
    float* buf0 = smem;
    float* buf1 = smem + 144;
    gj_block<0>(rr, buf0, buf1, irow, qq);
    gj_block<1>(rr, buf0, buf1, irow, qq);
    gj_block<2>(rr, buf0, buf1, irow, qq);
    gj_block<3>(rr, buf0, buf1, irow, qq);
    __syncthreads();
    #pragma unroll
    for (int j=0;j<32;j++) smem[irow*Nn + 32*qq + j] = rr[j];
  }
  __syncthreads();

  //---- Phase C: WtT[k][j] = (A*Minv)[j][k] -> wsWt (transposed!); c = Minv q ----
  {
    const int jr = t & 63, kc = t >> 6;
    v2f acc[3][8];
    #pragma unroll
    for (int a=0;a<3;a++)
      #pragma unroll
      for (int p=0;p<8;p++) acc[a][p] = (v2f){0.f,0.f};

    for (int mi=0; mi<32; mi++) {
      const v4f a0 = *(const v4f*)&Ab[(jr      )*Nn + 4*mi];
      const v4f a1 = *(const v4f*)&Ab[(jr +  64)*Nn + 4*mi];
      const v4f a2 = *(const v4f*)&Ab[(jr + 128)*Nn + 4*mi];
      const float am[3][4] = {{a0.x,a0.y,a0.z,a0.w},
                              {a1.x,a1.y,a1.z,a1.w},
                              {a2.x,a2.y,a2.z,a2.w}};
      #pragma unroll
      for (int q=0;q<4;q++) {
        const int m = 4*mi + q;
        const v4f w0 = *(const v4f*)&smem[m*Nn + 16*kc +  0];
        const v4f w1 = *(const v4f*)&smem[m*Nn + 16*kc +  4];
        const v4f w2 = *(const v4f*)&smem[m*Nn + 16*kc +  8];
        const v4f w3 = *(const v4f*)&smem[m*Nn + 16*kc + 12];
        const v2f wp[8] = {(v2f){w0.x,w0.y},(v2f){w0.z,w0.w},
                           (v2f){w1.x,w1.y},(v2f){w1.z,w1.w},
                           (v2f){w2.x,w2.y},(v2f){w2.z,w2.w},
                           (v2f){w3.x,w3.y},(v2f){w3.z,w3.w}};
        #pragma unroll
        for (int a=0;a<3;a++) {
          const v2f amv = (v2f){am[a][q], am[a][q]};
          #pragma unroll
          for (int p=0;p<8;p++) acc[a][p] += amv * wp[p];
        }
      }
    }
    // transposed store: WtT[col][j], lanes (jr) run along j -> coalesced
    float* wb = wsWt + (size_t)b*Nn*Mm;
    #pragma unroll
    for (int a=0;a<3;a++) {
      const int j = jr + 64*a;
      #pragma unroll
      for (int p=0;p<8;p++) {
        const int col = 16*kc + 2*p;
        wb[(size_t)(col    )*Mm + j] = acc[a][p].x;
        wb[(size_t)(col + 1)*Mm + j] = acc[a][p].y;
      }
    }
  }
  if (t < Nn) {
    float cc = 0.f;
    #pragma unroll 4
    for (int k=0;k<Nn;k++) cc += smem[k*Nn + t] * qb[k];
    wsC[(size_t)b*Nn + t] = cc;
  }
}

//======================= Kernel 2: row-per-lane V-space ADMM loop ==================
#define WT_LD 196                       // padded LDS row stride (floats), 16B-aligned
#define OFF_S0   (Nn*WT_LD)             // 25088
#define OFF_S1   (OFF_S0 + Mm)          // 25280
#define OFF_SACC (OFF_S1 + Mm)          // 25472
#define OFF_C    (OFF_SACC + Mm)        // 25664
#define OFF_FLAG (OFF_C + Nn)           // 25792
#define LOOP_LDS_FLOATS (OFF_FLAG + 2)  // 25794 floats = 103176 B

__global__ void __launch_bounds__(256)
__attribute__((amdgpu_waves_per_eu(1, 1)))
loop_kernel(const float* __restrict__ Ag, const float* __restrict__ lg,
            const float* __restrict__ ug, const float* __restrict__ wsWtT,
            const float* __restrict__ wsC, float* __restrict__ outg)
{
  extern __shared__ float smem[];
  const int t = threadIdx.x, b = blockIdx.x;
  const bool act = (t < Mm);
  const float* __restrict__ Wg = wsWtT + (size_t)b*Nn*Mm;   // [128][192]
  const float* __restrict__ cb = wsC  + (size_t)b*Nn;
  const float* __restrict__ Ab = Ag   + (size_t)b*Mm*Nn;

  float* WT    = smem;                 // [128][196]
  float* sT0   = smem + OFF_S0;
  float* sT1   = smem + OFF_S1;
  float* sacc  = smem + OFF_SACC;
  float* c_s   = smem + OFF_C;
  float* sflag = smem + OFF_FLAG;

  // ---- stage WtT into LDS (lane j = column j, coalesced global + conflict-free LDS)
  if (act) {
    #pragma unroll 4
    for (int k = 0; k < Nn; k++) WT[k*WT_LD + t] = Wg[(size_t)k*Mm + t];
  }
  if (t < Nn) c_s[t] = cb[t];
  if (act) sT0[t] = 0.f;
  if (t < 2) sflag[t] = 0.f;
  __syncthreads();

  // ---- d = A_t . c ; bounds ; V row (192 f32 in 96 v2f regs) ----
  float dreg = 0.f, lreg = 0.f, ureg = 0.f;
  v2f Vrow[96];
  if (act) {
    lreg = lg[(size_t)b*Mm + t];
    ureg = ug[(size_t)b*Mm + t];
    const float4* ar = (const float4*)(Ab + (size_t)t*Nn);
    const float4* cr = (const float4*)c_s;
    #pragma unroll 4
    for (int k4 = 0; k4 < 32; k4++) {
      const float4 av = ar[k4], cv = cr[k4];
      dreg += av.x*cv.x + av.y*cv.y + av.z*cv.z + av.w*cv.w;
    }
    #pragma unroll
    for (int p = 0; p < 96; p++) Vrow[p] = (v2f){0.f, 0.f};
    // V[t][:] = sum_k A[t][k] * WtT[k][:]  (WtT rows broadcast from LDS)
    for (int k2 = 0; k2 < 64; k2++) {
      const v2f a2 = *(const v2f*)&Ab[(size_t)t*Nn + 2*k2];
      const float* w0 = &WT[(2*k2    )*WT_LD];
      const float* w1 = &WT[(2*k2 + 1)*WT_LD];
      const v2f ax = (v2f){a2.x, a2.x};
      const v2f ay = (v2f){a2.y, a2.y};
      #pragma unroll
      for (int p4 = 0; p4 < 48; p4++) {
        const v4f wa = *(const v4f*)&w0[4*p4];
        const v4f wv = *(const v4f*)&w1[4*p4];
        Vrow[2*p4]   = __builtin_elementwise_fma(ax, (v2f){wa.x,wa.y}, Vrow[2*p4]);
        Vrow[2*p4+1] = __builtin_elementwise_fma(ax, (v2f){wa.z,wa.w}, Vrow[2*p4+1]);
        Vrow[2*p4]   = __builtin_elementwise_fma(ay, (v2f){wv.x,wv.y}, Vrow[2*p4]);
        Vrow[2*p4+1] = __builtin_elementwise_fma(ay, (v2f){wv.z,wv.w}, Vrow[2*p4+1]);
      }
    }
  }

  float sreg = 0.f, preg = 0.f, Sacc = 0.f;
  bool cvg = false;

#define ITER(RD, WR, CHK, PH)                                                  \
  {                                                                            \
    if (act) {                                                                 \
      v2f q0 = (v2f){0.f,0.f}, q1 = (v2f){0.f,0.f};                            \
      v2f q2 = (v2f){0.f,0.f}, q3 = (v2f){0.f,0.f};                            \
      _Pragma("unroll")                                                        \
      for (int p4 = 0; p4 < 24; p4++) {                                        \
        const v4f sv = *(const v4f*)&(RD)[4*p4];                               \
        const v4f sw = *(const v4f*)&(RD)[4*p4 + 96];                          \
        q0 = __builtin_elementwise_fma(Vrow[2*p4],    (v2f){sv.x,sv.y}, q0);   \
        q1 = __builtin_elementwise_fma(Vrow[2*p4+1],  (v2f){sv.z,sv.w}, q1);   \
        q2 = __builtin_elementwise_fma(Vrow[2*p4+48], (v2f){sw.x,sw.y}, q2);   \
        q3 = __builtin_elementwise_fma(Vrow[2*p4+49], (v2f){sw.z,sw.w}, q3);   \
      }                                                                        \
      q0 += q1; q2 += q3; q0 += q2;                                            \
      const float r  = q0.x + q0.y;                                            \
      const float w  = r - dreg;                                               \
      const float v  = fmaf(ALPHA_, w, preg);                                  \
      const float z  = __builtin_amdgcn_fmed3f(v, lreg, ureg);                 \
      const float sn = RHO_ * fmaf(2.0f, z, -v);                               \
      const float pn = fmaf(-ALPHA_, z, v);                                    \
      (WR)[t] = sn;                                                            \
      if (CHK) { if (!(sn == sreg && pn == preg)) sflag[PH] = 1.f; }           \
      Sacc = fmaf(1.0f - ALPHA_, Sacc, ALPHA_ * sreg);                         \
      sreg = sn; preg = pn;                                                    \
    }                                                                          \
    if ((CHK) && t == 0) sflag[(PH) ^ 1] = 0.f;                                \
    __syncthreads();                                                           \
    if (CHK) cvg = (sflag[PH] == 0.f);                                         \
  }

  #pragma unroll 1
  for (int it2 = 0; it2 < NITERS_/2; it2++) {
    ITER(sT0, sT1, false, 0)
    const bool chk = ((it2 & 3) == 3) && (it2 < NITERS_/2 - 40);
    const int ph = (it2 >> 2) & 1;
    ITER(sT1, sT0, chk, ph)
    if (cvg) break;   // bitwise fixed point: remaining iterations are identities
  }
#undef ITER
  if (cvg && act) Sacc = sreg;   // Sacc -> s* geometrically; |(-0.6)^80| ~ 2e-18

  // ---- epilogue: x = Wt^T Sacc - c  (= WtT rows . Sacc) ----
  if (act) sacc[t] = Sacc;
  __syncthreads();
  if (t < Nn) {
    const float* wr = &WT[t*WT_LD];
    v2f xa = (v2f){0.f,0.f}, xb = (v2f){0.f,0.f};
    #pragma unroll
    for (int j4 = 0; j4 < 48; j4++) {
      const v4f wv = *(const v4f*)&wr[4*j4];
      const v4f sv = *(const v4f*)&sacc[4*j4];
      xa = __builtin_elementwise_fma((v2f){wv.x,wv.y}, (v2f){sv.x,sv.y}, xa);
      xb = __builtin_elementwise_fma((v2f){wv.z,wv.w}, (v2f){sv.z,sv.w}, xb);
    }
    xa += xb;
    outg[(size_t)b*Nn + t] = xa.x + xa.y - c_s[t];
  }
}

extern "C" void kernel_launch(void* const* d_in, const int* in_sizes, int n_in,
                              void* d_out, int out_size, void* d_ws, size_t ws_size,
                              hipStream_t stream) {
  const float* P = (const float*)d_in[0];
  const float* q = (const float*)d_in[1];
  const float* A = (const float*)d_in[2];
  const float* l = (const float*)d_in[3];
  const float* u = (const float*)d_in[4];
  (void)in_sizes; (void)n_in; (void)out_size; (void)ws_size;
  float* wsWt = (float*)d_ws;                      // WtT: 256*128*192 floats = 25.2 MB
  float* wsC  = wsWt + (size_t)256*Mm*Nn;          // 256*128 floats
  precompute_kernel<<<256, 512, 0, stream>>>(P, q, A, wsWt, wsC);
  loop_kernel<<<256, 256, LOOP_LDS_FLOATS*4, stream>>>(A, l, u, wsWt, wsC, (float*)d_out);
}

// Round 2
// 521.745 us; speedup vs baseline: 1.2848x; 1.2848x over previous
//
#include <hip/hip_runtime.h>

// OSQP batched ADMM, B=256 N=128 M=192, 400 iters.
// R7: R6 row-per-lane design with the register budget actually applied.
// R6 failed because amdgpu_waves_per_eu in declarator position was silently
// dropped -> 128-VGPR cap -> Vrow[96 v2f] spilled to scratch (VGPR_Count=132,
// ~15GB L2 scratch traffic = the 515us). R7: __launch_bounds__(256, 1)
// (2nd arg = min waves/EU, the supported path) + chunked dot (24-float s
// chunks) to bound in-flight liveness. 256 thr/block: rows 0..191 in waves
// 0-2, wave 3 idle in loop (barrier only). s exchanged via plain LDS s[j]
// (wave-uniform broadcast ds_read_b128, conflict-free). Bitwise fixed-point
// early exit kept (exact; validated R6).
// Algebra: M = P + sI + rho*AtA (SPD);  Wt = A*Minv;  c = Minv q
//   V = A Minv At;  d = A c
//   iterate (s_0=0), state (p, s, Sacc):
//     r = V s ; w = r - d ; v = a*w + p ; z = med3(v,l,u) ;
//     s' = rho*(2z - v) ; Sacc' = (1-a)Sacc + a*s ; p' = v - a*z
//   epilogue: x = Wt^T Sacc - c

#define Nn 128
#define Mm 192
constexpr float RHO_    = 0.1f;
constexpr float SIGMA_  = 1e-6f;
constexpr float ALPHA_  = 1.6f;
constexpr int   NITERS_ = 400;

typedef float v2f __attribute__((ext_vector_type(2)));
typedef float v4f __attribute__((ext_vector_type(4)));

//======================= Kernel 1: precompute WtT, c ===============================
// [R3-validated GJ core, unchanged]
template<int K0>
__device__ __forceinline__ void gj_block(float rr[32], float* __restrict__ buf0,
                                         float* __restrict__ buf1,
                                         const int irow, const int qq) {
  const bool qsel = (qq == K0);
  #pragma unroll
  for (int kk = 0; kk < 32; kk++) {
    const int k = 32*K0 + kk;
    float* wb = ((kk & 1) == 0) ? buf0 : buf1;
    if (irow == k) {
      #pragma unroll
      for (int j4 = 0; j4 < 8; j4++)
        *(float4*)&wb[36*qq + 4*j4] = *(const float4*)&rr[4*j4];
    }
    __syncthreads();
    const float akk  = wb[36*K0 + kk];
    float pinv = __builtin_amdgcn_rcpf(akk);
    pinv = pinv + pinv*(1.0f - akk*pinv);
    constexpr int QP = K0 | (K0<<2) | (K0<<4) | (K0<<6);
    const int fi = __builtin_amdgcn_update_dpp(__float_as_int(rr[kk]),
                      __float_as_int(rr[kk]), QP, 0xF, 0xF, false);
    const float f = __int_as_float(fi);
    const bool piv = (irow == k);
    float gfac = f * pinv;
    gfac = piv ? (1.0f - pinv) : gfac;
    float rk[32];
    #pragma unroll
    for (int j4 = 0; j4 < 8; j4++)
      *(float4*)&rk[4*j4] = *(const float4*)&wb[36*qq + 4*j4];
    #pragma unroll
    for (int j = 0; j < 32; j++) rr[j] -= gfac * rk[j];
    const float pivfix = piv ? pinv : -gfac;
    if (qsel) rr[kk] = pivfix;
  }
}

__global__ void __launch_bounds__(512, 2)
precompute_kernel(const float* __restrict__ Pg, const float* __restrict__ qg,
                  const float* __restrict__ Ag, float* __restrict__ wsWt,
                  float* __restrict__ wsC)
{
  __shared__ float smem[16384];
  const int t = threadIdx.x;
  const int b = blockIdx.x;
  const float* __restrict__ Pb = Pg + (size_t)b*Nn*Nn;
  const float* __restrict__ qb = qg + (size_t)b*Nn;
  const float* __restrict__ Ab = Ag + (size_t)b*Mm*Nn;

  //---- Phase A: S = P + sigma*I + rho * A^T A ----
  {
    const int ar = t & 31;
    const int bc = t >> 5;
    float acc[4][8];
    #pragma unroll
    for (int a=0;a<4;a++)
      #pragma unroll
      for (int j=0;j<8;j++) acc[a][j]=0.f;

    for (int c=0;c<6;c++) {
      __syncthreads();
      {
        const float4* src = (const float4*)(Ab + c*32*Nn);
        float4* dst = (float4*)smem;
        dst[t]     = src[t];
        dst[t+512] = src[t+512];
      }
      __syncthreads();
      #pragma unroll 2
      for (int m=0;m<32;m++) {
        const float4 ra  = *(const float4*)&smem[m*Nn + 4*ar];
        const float4 cb0 = *(const float4*)&smem[m*Nn + 8*bc];
        const float4 cb1 = *(const float4*)&smem[m*Nn + 8*bc + 4];
        const float rv[4] = {ra.x, ra.y, ra.z, ra.w};
        const float cv[8] = {cb0.x,cb0.y,cb0.z,cb0.w,cb1.x,cb1.y,cb1.z,cb1.w};
        #pragma unroll
        for (int a=0;a<4;a++)
          #pragma unroll
          for (int j=0;j<8;j++) acc[a][j] += rv[a]*cv[j];
      }
    }
    __syncthreads();
    #pragma unroll
    for (int a=0;a<4;a++) {
      const int i = 4*ar + a;
      #pragma unroll
      for (int j=0;j<8;j++) {
        const int jj = 8*bc + j;
        float v = Pb[i*Nn + jj] + RHO_*acc[a][j];
        if (i == jj) v += SIGMA_;
        smem[i*Nn + jj] = v;
      }
    }
    __syncthreads();
  }

  //---- Phase B: Gauss-Jordan inverse ----
  {
    const int irow = t >> 2;
    const int qq   = t & 3;
    float rr[32];
    #pragma unroll
    for (int j=0;j<32;j++) rr[j] = smem[irow*Nn + 32*qq + j];
    __syncthreads();
    float* buf0 = smem;
    float* buf1 = smem + 144;
    gj_block<0>(rr, buf0, buf1, irow, qq);
    gj_block<1>(rr, buf0, buf1, irow, qq);
    gj_block<2>(rr, buf0, buf1, irow, qq);
    gj_block<3>(rr, buf0, buf1, irow, qq);
    __syncthreads();
    #pragma unroll
    for (int j=0;j<32;j++) smem[irow*Nn + 32*qq + j] = rr[j];
  }
  __syncthreads();

  //---- Phase C: WtT[k][j] = (A*Minv)[j][k] -> wsWt (transposed!); c = Minv q ----
  {
    const int jr = t & 63, kc = t >> 6;
    v2f acc[3][8];
    #pragma unroll
    for (int a=0;a<3;a++)
      #pragma unroll
      for (int p=0;p<8;p++) acc[a][p] = (v2f){0.f,0.f};

    for (int mi=0; mi<32; mi++) {
      const v4f a0 = *(const v4f*)&Ab[(jr      )*Nn + 4*mi];
      const v4f a1 = *(const v4f*)&Ab[(jr +  64)*Nn + 4*mi];
      const v4f a2 = *(const v4f*)&Ab[(jr + 128)*Nn + 4*mi];
      const float am[3][4] = {{a0.x,a0.y,a0.z,a0.w},
                              {a1.x,a1.y,a1.z,a1.w},
                              {a2.x,a2.y,a2.z,a2.w}};
      #pragma unroll
      for (int q=0;q<4;q++) {
        const int m = 4*mi + q;
        const v4f w0 = *(const v4f*)&smem[m*Nn + 16*kc +  0];
        const v4f w1 = *(const v4f*)&smem[m*Nn + 16*kc +  4];
        const v4f w2 = *(const v4f*)&smem[m*Nn + 16*kc +  8];
        const v4f w3 = *(const v4f*)&smem[m*Nn + 16*kc + 12];
        const v2f wp[8] = {(v2f){w0.x,w0.y},(v2f){w0.z,w0.w},
                           (v2f){w1.x,w1.y},(v2f){w1.z,w1.w},
                           (v2f){w2.x,w2.y},(v2f){w2.z,w2.w},
                           (v2f){w3.x,w3.y},(v2f){w3.z,w3.w}};
        #pragma unroll
        for (int a=0;a<3;a++) {
          const v2f amv = (v2f){am[a][q], am[a][q]};
          #pragma unroll
          for (int p=0;p<8;p++) acc[a][p] += amv * wp[p];
        }
      }
    }
    // transposed store: WtT[col][j], lanes (jr) run along j -> coalesced
    float* wb = wsWt + (size_t)b*Nn*Mm;
    #pragma unroll
    for (int a=0;a<3;a++) {
      const int j = jr + 64*a;
      #pragma unroll
      for (int p=0;p<8;p++) {
        const int col = 16*kc + 2*p;
        wb[(size_t)(col    )*Mm + j] = acc[a][p].x;
        wb[(size_t)(col + 1)*Mm + j] = acc[a][p].y;
      }
    }
  }
  if (t < Nn) {
    float cc = 0.f;
    #pragma unroll 4
    for (int k=0;k<Nn;k++) cc += smem[k*Nn + t] * qb[k];
    wsC[(size_t)b*Nn + t] = cc;
  }
}

//======================= Kernel 2: row-per-lane V-space ADMM loop ==================
#define WT_LD 196                       // padded LDS row stride (floats), 16B-aligned
#define OFF_S0   (Nn*WT_LD)             // 25088
#define OFF_S1   (OFF_S0 + Mm)          // 25280
#define OFF_SACC (OFF_S1 + Mm)          // 25472
#define OFF_C    (OFF_SACC + Mm)        // 25664
#define OFF_FLAG (OFF_C + Nn)           // 25792
#define LOOP_LDS_FLOATS (OFF_FLAG + 2)  // 25794 floats = 103176 B

// __launch_bounds__(256, 1): 2nd arg = min waves per EU = 1 -> RA budget 512
// regs (256 arch VGPR + AGPR overflow). This is the supported spelling; the
// amdgpu_waves_per_eu attribute in declarator position (R6) was dropped.
__global__ __launch_bounds__(256, 1) void
loop_kernel(const float* __restrict__ Ag, const float* __restrict__ lg,
            const float* __restrict__ ug, const float* __restrict__ wsWtT,
            const float* __restrict__ wsC, float* __restrict__ outg)
{
  extern __shared__ float smem[];
  const int t = threadIdx.x, b = blockIdx.x;
  const bool act = (t < Mm);
  const float* __restrict__ Wg = wsWtT + (size_t)b*Nn*Mm;   // [128][192]
  const float* __restrict__ cb = wsC  + (size_t)b*Nn;
  const float* __restrict__ Ab = Ag   + (size_t)b*Mm*Nn;

  float* WT    = smem;                 // [128][196]
  float* sT0   = smem + OFF_S0;
  float* sT1   = smem + OFF_S1;
  float* sacc  = smem + OFF_SACC;
  float* c_s   = smem + OFF_C;
  float* sflag = smem + OFF_FLAG;

  // ---- stage WtT into LDS (lane j = column j, coalesced global, conflict-free LDS)
  if (act) {
    #pragma unroll 4
    for (int k = 0; k < Nn; k++) WT[k*WT_LD + t] = Wg[(size_t)k*Mm + t];
  }
  if (t < Nn) c_s[t] = cb[t];
  if (act) sT0[t] = 0.f;
  if (t < 2) sflag[t] = 0.f;
  __syncthreads();

  // ---- d = A_t . c ; bounds ; V row (192 f32 = 96 v2f regs) ----
  float dreg = 0.f, lreg = 0.f, ureg = 0.f;
  v2f Vrow[96];
  if (act) {
    lreg = lg[(size_t)b*Mm + t];
    ureg = ug[(size_t)b*Mm + t];
    const float4* ar = (const float4*)(Ab + (size_t)t*Nn);
    const float4* cr = (const float4*)c_s;
    #pragma unroll 4
    for (int k4 = 0; k4 < 32; k4++) {
      const float4 av = ar[k4], cv = cr[k4];
      dreg += av.x*cv.x + av.y*cv.y + av.z*cv.z + av.w*cv.w;
    }
    #pragma unroll
    for (int p = 0; p < 96; p++) Vrow[p] = (v2f){0.f, 0.f};
    // V[t][:] = sum_k A[t][k] * WtT[k][:]  (WtT rows broadcast from LDS)
    for (int k4 = 0; k4 < 32; k4++) {
      const v4f a4 = *(const v4f*)&Ab[(size_t)t*Nn + 4*k4];
      const float aks[4] = {a4.x, a4.y, a4.z, a4.w};
      #pragma unroll
      for (int kk = 0; kk < 4; kk++) {
        const v2f av = (v2f){aks[kk], aks[kk]};
        const float* w = &WT[(4*k4 + kk)*WT_LD];
        // chunked: 8 chunks x (6 ds_read_b128 + 12 pk_fma) bounds liveness
        #pragma unroll
        for (int ch = 0; ch < 8; ch++) {
          const float* wp = w + 24*ch;
          const v4f w0 = *(const v4f*)&wp[0];
          const v4f w1 = *(const v4f*)&wp[4];
          const v4f w2 = *(const v4f*)&wp[8];
          const v4f w3 = *(const v4f*)&wp[12];
          const v4f w4 = *(const v4f*)&wp[16];
          const v4f w5 = *(const v4f*)&wp[20];
          Vrow[12*ch+ 0] = __builtin_elementwise_fma(av, (v2f){w0.x,w0.y}, Vrow[12*ch+ 0]);
          Vrow[12*ch+ 1] = __builtin_elementwise_fma(av, (v2f){w0.z,w0.w}, Vrow[12*ch+ 1]);
          Vrow[12*ch+ 2] = __builtin_elementwise_fma(av, (v2f){w1.x,w1.y}, Vrow[12*ch+ 2]);
          Vrow[12*ch+ 3] = __builtin_elementwise_fma(av, (v2f){w1.z,w1.w}, Vrow[12*ch+ 3]);
          Vrow[12*ch+ 4] = __builtin_elementwise_fma(av, (v2f){w2.x,w2.y}, Vrow[12*ch+ 4]);
          Vrow[12*ch+ 5] = __builtin_elementwise_fma(av, (v2f){w2.z,w2.w}, Vrow[12*ch+ 5]);
          Vrow[12*ch+ 6] = __builtin_elementwise_fma(av, (v2f){w3.x,w3.y}, Vrow[12*ch+ 6]);
          Vrow[12*ch+ 7] = __builtin_elementwise_fma(av, (v2f){w3.z,w3.w}, Vrow[12*ch+ 7]);
          Vrow[12*ch+ 8] = __builtin_elementwise_fma(av, (v2f){w4.x,w4.y}, Vrow[12*ch+ 8]);
          Vrow[12*ch+ 9] = __builtin_elementwise_fma(av, (v2f){w4.z,w4.w}, Vrow[12*ch+ 9]);
          Vrow[12*ch+10] = __builtin_elementwise_fma(av, (v2f){w5.x,w5.y}, Vrow[12*ch+10]);
          Vrow[12*ch+11] = __builtin_elementwise_fma(av, (v2f){w5.z,w5.w}, Vrow[12*ch+11]);
        }
      }
    }
  }

  float sreg = 0.f, preg = 0.f, Sacc = 0.f;
  bool cvg = false;

#define ITER(RD, WR, CHK, PH)                                                  \
  {                                                                            \
    if (act) {                                                                 \
      v2f q0=(v2f){0.f,0.f}, q1=(v2f){0.f,0.f};                                \
      v2f q2=(v2f){0.f,0.f}, q3=(v2f){0.f,0.f};                                \
      _Pragma("unroll")                                                        \
      for (int ch = 0; ch < 8; ch++) {                                         \
        const float* rp = (RD) + 24*ch;                                        \
        const v4f sa = *(const v4f*)&rp[0];                                    \
        const v4f sb = *(const v4f*)&rp[4];                                    \
        const v4f sc = *(const v4f*)&rp[8];                                    \
        const v4f sd = *(const v4f*)&rp[12];                                   \
        const v4f se = *(const v4f*)&rp[16];                                   \
        const v4f sf = *(const v4f*)&rp[20];                                   \
        q0 = __builtin_elementwise_fma(Vrow[12*ch+ 0], (v2f){sa.x,sa.y}, q0);  \
        q1 = __builtin_elementwise_fma(Vrow[12*ch+ 1], (v2f){sa.z,sa.w}, q1);  \
        q2 = __builtin_elementwise_fma(Vrow[12*ch+ 2], (v2f){sb.x,sb.y}, q2);  \
        q3 = __builtin_elementwise_fma(Vrow[12*ch+ 3], (v2f){sb.z,sb.w}, q3);  \
        q0 = __builtin_elementwise_fma(Vrow[12*ch+ 4], (v2f){sc.x,sc.y}, q0);  \
        q1 = __builtin_elementwise_fma(Vrow[12*ch+ 5], (v2f){sc.z,sc.w}, q1);  \
        q2 = __builtin_elementwise_fma(Vrow[12*ch+ 6], (v2f){sd.x,sd.y}, q2);  \
        q3 = __builtin_elementwise_fma(Vrow[12*ch+ 7], (v2f){sd.z,sd.w}, q3);  \
        q0 = __builtin_elementwise_fma(Vrow[12*ch+ 8], (v2f){se.x,se.y}, q0);  \
        q1 = __builtin_elementwise_fma(Vrow[12*ch+ 9], (v2f){se.z,se.w}, q1);  \
        q2 = __builtin_elementwise_fma(Vrow[12*ch+10], (v2f){sf.x,sf.y}, q2);  \
        q3 = __builtin_elementwise_fma(Vrow[12*ch+11], (v2f){sf.z,sf.w}, q3);  \
      }                                                                        \
      q0 += q1; q2 += q3; q0 += q2;                                            \
      const float r  = q0.x + q0.y;                                            \
      const float w  = r - dreg;                                               \
      const float v  = fmaf(ALPHA_, w, preg);                                  \
      const float z  = __builtin_amdgcn_fmed3f(v, lreg, ureg);                 \
      const float sn = RHO_ * fmaf(2.0f, z, -v);                               \
      const float pn = fmaf(-ALPHA_, z, v);                                    \
      (WR)[t] = sn;                                                            \
      if (CHK) { if (!(sn == sreg && pn == preg)) sflag[PH] = 1.f; }           \
      Sacc = fmaf(1.0f - ALPHA_, Sacc, ALPHA_ * sreg);                         \
      sreg = sn; preg = pn;                                                    \
    }                                                                          \
    if ((CHK) && t == 0) sflag[(PH) ^ 1] = 0.f;                                \
    __syncthreads();                                                           \
    if (CHK) cvg = (sflag[PH] == 0.f);                                         \
  }

  #pragma unroll 1
  for (int it2 = 0; it2 < NITERS_/2; it2++) {
    ITER(sT0, sT1, false, 0)
    const bool chk = ((it2 & 3) == 3) && (it2 < NITERS_/2 - 40);
    const int ph = (it2 >> 2) & 1;
    ITER(sT1, sT0, chk, ph)
    if (cvg) break;   // bitwise fixed point: remaining iterations are identities
  }
#undef ITER
  if (cvg && act) Sacc = sreg;   // Sacc -> s* geometrically; |(-0.6)^80| ~ 2e-18

  // ---- epilogue: x = Wt^T Sacc - c  (= WtT rows . Sacc) ----
  if (act) sacc[t] = Sacc;
  __syncthreads();
  if (t < Nn) {
    const float* wr = &WT[t*WT_LD];
    v2f xa = (v2f){0.f,0.f}, xb = (v2f){0.f,0.f};
    #pragma unroll
    for (int j4 = 0; j4 < 48; j4++) {
      const v4f wv = *(const v4f*)&wr[4*j4];
      const v4f sv = *(const v4f*)&sacc[4*j4];
      xa = __builtin_elementwise_fma((v2f){wv.x,wv.y}, (v2f){sv.x,sv.y}, xa);
      xb = __builtin_elementwise_fma((v2f){wv.z,wv.w}, (v2f){sv.z,sv.w}, xb);
    }
    xa += xb;
    outg[(size_t)b*Nn + t] = xa.x + xa.y - c_s[t];
  }
}

extern "C" void kernel_launch(void* const* d_in, const int* in_sizes, int n_in,
                              void* d_out, int out_size, void* d_ws, size_t ws_size,
                              hipStream_t stream) {
  const float* P = (const float*)d_in[0];
  const float* q = (const float*)d_in[1];
  const float* A = (const float*)d_in[2];
  const float* l = (const float*)d_in[3];
  const float* u = (const float*)d_in[4];
  (void)in_sizes; (void)n_in; (void)out_size; (void)ws_size;
  float* wsWt = (float*)d_ws;                      // WtT: 256*128*192 floats = 25.2 MB
  float* wsC  = wsWt + (size_t)256*Mm*Nn;          // 256*128 floats
  precompute_kernel<<<256, 512, 0, stream>>>(P, q, A, wsWt, wsC);
  loop_kernel<<<256, 256, LOOP_LDS_FLOATS*4, stream>>>(A, l, u, wsWt, wsC, (float*)d_out);
}

// Round 3
// 425.278 us; speedup vs baseline: 1.5762x; 1.2268x over previous
//
#include <hip/hip_runtime.h>

// OSQP batched ADMM, B=256 N=128 M=192, 400 iters.
// R8: quarter-row split. R6/R7 both failed to get a >128-VGPR budget out of
// the RA (VGPR_Count 132/140, Vrow spilled to scratch -> 515/366us). R8 stops
// fighting: 768 thr/block (12 waves, 3/SIMD), each V row j owned by 4 lanes
// of ONE wave (lane qt=(t>>4)&3 holds Vq[24 v2f]=48 VGPR, ~100 total -> no
// spill possible). Quarter partials combined with 2x __shfl_xor(16/32);
// all 4 lanes get bitwise-identical r -> scalar chain redundant, no
// divergence, 1 barrier/iter. s-segment reads are 4-address/wave broadcast
// (2-way bank alias = free). WT LDS staging, plain-s double buffer, bitwise
// early exit, epilogue all kept from validated R7.
// Algebra: M = P + sI + rho*AtA (SPD);  Wt = A*Minv;  c = Minv q
//   V = A Minv At;  d = A c
//   iterate (s_0=0), state (p, s, Sacc):
//     r = V s ; w = r - d ; v = a*w + p ; z = med3(v,l,u) ;
//     s' = rho*(2z - v) ; Sacc' = (1-a)Sacc + a*s ; p' = v - a*z
//   epilogue: x = Wt^T Sacc - c

#define Nn 128
#define Mm 192
constexpr float RHO_    = 0.1f;
constexpr float SIGMA_  = 1e-6f;
constexpr float ALPHA_  = 1.6f;
constexpr int   NITERS_ = 400;

typedef float v2f __attribute__((ext_vector_type(2)));
typedef float v4f __attribute__((ext_vector_type(4)));

//======================= Kernel 1: precompute WtT, c ===============================
// [R3-validated GJ core, unchanged]
template<int K0>
__device__ __forceinline__ void gj_block(float rr[32], float* __restrict__ buf0,
                                         float* __restrict__ buf1,
                                         const int irow, const int qq) {
  const bool qsel = (qq == K0);
  #pragma unroll
  for (int kk = 0; kk < 32; kk++) {
    const int k = 32*K0 + kk;
    float* wb = ((kk & 1) == 0) ? buf0 : buf1;
    if (irow == k) {
      #pragma unroll
      for (int j4 = 0; j4 < 8; j4++)
        *(float4*)&wb[36*qq + 4*j4] = *(const float4*)&rr[4*j4];
    }
    __syncthreads();
    const float akk  = wb[36*K0 + kk];
    float pinv = __builtin_amdgcn_rcpf(akk);
    pinv = pinv + pinv*(1.0f - akk*pinv);
    constexpr int QP = K0 | (K0<<2) | (K0<<4) | (K0<<6);
    const int fi = __builtin_amdgcn_update_dpp(__float_as_int(rr[kk]),
                      __float_as_int(rr[kk]), QP, 0xF, 0xF, false);
    const float f = __int_as_float(fi);
    const bool piv = (irow == k);
    float gfac = f * pinv;
    gfac = piv ? (1.0f - pinv) : gfac;
    float rk[32];
    #pragma unroll
    for (int j4 = 0; j4 < 8; j4++)
      *(float4*)&rk[4*j4] = *(const float4*)&wb[36*qq + 4*j4];
    #pragma unroll
    for (int j = 0; j < 32; j++) rr[j] -= gfac * rk[j];
    const float pivfix = piv ? pinv : -gfac;
    if (qsel) rr[kk] = pivfix;
  }
}

__global__ void __launch_bounds__(512, 2)
precompute_kernel(const float* __restrict__ Pg, const float* __restrict__ qg,
                  const float* __restrict__ Ag, float* __restrict__ wsWt,
                  float* __restrict__ wsC)
{
  __shared__ float smem[16384];
  const int t = threadIdx.x;
  const int b = blockIdx.x;
  const float* __restrict__ Pb = Pg + (size_t)b*Nn*Nn;
  const float* __restrict__ qb = qg + (size_t)b*Nn;
  const float* __restrict__ Ab = Ag + (size_t)b*Mm*Nn;

  //---- Phase A: S = P + sigma*I + rho * A^T A ----
  {
    const int ar = t & 31;
    const int bc = t >> 5;
    float acc[4][8];
    #pragma unroll
    for (int a=0;a<4;a++)
      #pragma unroll
      for (int j=0;j<8;j++) acc[a][j]=0.f;

    for (int c=0;c<6;c++) {
      __syncthreads();
      {
        const float4* src = (const float4*)(Ab + c*32*Nn);
        float4* dst = (float4*)smem;
        dst[t]     = src[t];
        dst[t+512] = src[t+512];
      }
      __syncthreads();
      #pragma unroll 2
      for (int m=0;m<32;m++) {
        const float4 ra  = *(const float4*)&smem[m*Nn + 4*ar];
        const float4 cb0 = *(const float4*)&smem[m*Nn + 8*bc];
        const float4 cb1 = *(const float4*)&smem[m*Nn + 8*bc + 4];
        const float rv[4] = {ra.x, ra.y, ra.z, ra.w};
        const float cv[8] = {cb0.x,cb0.y,cb0.z,cb0.w,cb1.x,cb1.y,cb1.z,cb1.w};
        #pragma unroll
        for (int a=0;a<4;a++)
          #pragma unroll
          for (int j=0;j<8;j++) acc[a][j] += rv[a]*cv[j];
      }
    }
    __syncthreads();
    #pragma unroll
    for (int a=0;a<4;a++) {
      const int i = 4*ar + a;
      #pragma unroll
      for (int j=0;j<8;j++) {
        const int jj = 8*bc + j;
        float v = Pb[i*Nn + jj] + RHO_*acc[a][j];
        if (i == jj) v += SIGMA_;
        smem[i*Nn + jj] = v;
      }
    }
    __syncthreads();
  }

  //---- Phase B: Gauss-Jordan inverse ----
  {
    const int irow = t >> 2;
    const int qq   = t & 3;
    float rr[32];
    #pragma unroll
    for (int j=0;j<32;j++) rr[j] = smem[irow*Nn + 32*qq + j];
    __syncthreads();
    float* buf0 = smem;
    float* buf1 = smem + 144;
    gj_block<0>(rr, buf0, buf1, irow, qq);
    gj_block<1>(rr, buf0, buf1, irow, qq);
    gj_block<2>(rr, buf0, buf1, irow, qq);
    gj_block<3>(rr, buf0, buf1, irow, qq);
    __syncthreads();
    #pragma unroll
    for (int j=0;j<32;j++) smem[irow*Nn + 32*qq + j] = rr[j];
  }
  __syncthreads();

  //---- Phase C: WtT[k][j] = (A*Minv)[j][k] -> wsWt (transposed!); c = Minv q ----
  {
    const int jr = t & 63, kc = t >> 6;
    v2f acc[3][8];
    #pragma unroll
    for (int a=0;a<3;a++)
      #pragma unroll
      for (int p=0;p<8;p++) acc[a][p] = (v2f){0.f,0.f};

    for (int mi=0; mi<32; mi++) {
      const v4f a0 = *(const v4f*)&Ab[(jr      )*Nn + 4*mi];
      const v4f a1 = *(const v4f*)&Ab[(jr +  64)*Nn + 4*mi];
      const v4f a2 = *(const v4f*)&Ab[(jr + 128)*Nn + 4*mi];
      const float am[3][4] = {{a0.x,a0.y,a0.z,a0.w},
                              {a1.x,a1.y,a1.z,a1.w},
                              {a2.x,a2.y,a2.z,a2.w}};
      #pragma unroll
      for (int q=0;q<4;q++) {
        const int m = 4*mi + q;
        const v4f w0 = *(const v4f*)&smem[m*Nn + 16*kc +  0];
        const v4f w1 = *(const v4f*)&smem[m*Nn + 16*kc +  4];
        const v4f w2 = *(const v4f*)&smem[m*Nn + 16*kc +  8];
        const v4f w3 = *(const v4f*)&smem[m*Nn + 16*kc + 12];
        const v2f wp[8] = {(v2f){w0.x,w0.y},(v2f){w0.z,w0.w},
                           (v2f){w1.x,w1.y},(v2f){w1.z,w1.w},
                           (v2f){w2.x,w2.y},(v2f){w2.z,w2.w},
                           (v2f){w3.x,w3.y},(v2f){w3.z,w3.w}};
        #pragma unroll
        for (int a=0;a<3;a++) {
          const v2f amv = (v2f){am[a][q], am[a][q]};
          #pragma unroll
          for (int p=0;p<8;p++) acc[a][p] += amv * wp[p];
        }
      }
    }
    // transposed store: WtT[col][j], lanes (jr) run along j -> coalesced
    float* wb = wsWt + (size_t)b*Nn*Mm;
    #pragma unroll
    for (int a=0;a<3;a++) {
      const int j = jr + 64*a;
      #pragma unroll
      for (int p=0;p<8;p++) {
        const int col = 16*kc + 2*p;
        wb[(size_t)(col    )*Mm + j] = acc[a][p].x;
        wb[(size_t)(col + 1)*Mm + j] = acc[a][p].y;
      }
    }
  }
  if (t < Nn) {
    float cc = 0.f;
    #pragma unroll 4
    for (int k=0;k<Nn;k++) cc += smem[k*Nn + t] * qb[k];
    wsC[(size_t)b*Nn + t] = cc;
  }
}

//======================= Kernel 2: quarter-row V-space ADMM loop ===================
#define WT_LD 196                       // padded LDS row stride (floats), 16B-aligned
#define OFF_S0   (Nn*WT_LD)             // 25088
#define OFF_S1   (OFF_S0 + Mm)          // 25280
#define OFF_SACC (OFF_S1 + Mm)          // 25472
#define OFF_C    (OFF_SACC + Mm)        // 25664
#define OFF_FLAG (OFF_C + Nn)           // 25792
#define LOOP_LDS_FLOATS (OFF_FLAG + 2)  // 25794 floats = 103176 B

// 768 threads = 12 waves = 3 waves/EU (2nd arg). Per-lane needs ~100 VGPR
// (Vq 48 + working) -> fits the 512/3=170 cap with margin; no spill.
__global__ __launch_bounds__(768, 3) void
loop_kernel(const float* __restrict__ Ag, const float* __restrict__ lg,
            const float* __restrict__ ug, const float* __restrict__ wsWtT,
            const float* __restrict__ wsC, float* __restrict__ outg)
{
  extern __shared__ float smem[];
  const int t = threadIdx.x, b = blockIdx.x;
  const int qt = (t >> 4) & 3;                 // quarter 0..3 (s-cols 48qt..48qt+47)
  const int j  = ((t >> 6) << 4) | (t & 15);   // row 0..191 (wave w owns rows 16w..16w+15)
  const bool wlane = (qt == 0);
  const float* __restrict__ Wg = wsWtT + (size_t)b*Nn*Mm;   // [128][192]
  const float* __restrict__ cb = wsC  + (size_t)b*Nn;
  const float* __restrict__ Ab = Ag   + (size_t)b*Mm*Nn;

  float* WT    = smem;                 // [128][196]
  float* sT0   = smem + OFF_S0;
  float* sT1   = smem + OFF_S1;
  float* sacc  = smem + OFF_SACC;
  float* c_s   = smem + OFF_C;
  float* sflag = smem + OFF_FLAG;

  // ---- stage WtT into LDS: thread covers col jc for 32 rows (coalesced both sides)
  {
    const int jc = t % 192;
    const int g  = t / 192;              // 0..3
    #pragma unroll 4
    for (int i = 0; i < 32; i++) {
      const int k = 32*g + i;
      WT[k*WT_LD + jc] = Wg[(size_t)k*Mm + jc];
    }
  }
  if (t < Nn) c_s[t] = cb[t];
  if (t < Mm) sT0[t] = 0.f;
  if (t < 2) sflag[t] = 0.f;
  __syncthreads();

  // ---- bounds (all 4 quarter-lanes load same value: broadcast) ----
  const float lreg = lg[(size_t)b*Mm + j];
  const float ureg = ug[(size_t)b*Mm + j];
  const float* Arow = Ab + (size_t)j*Nn;

  // ---- d = A_j . c  (quarter partial over k in [32qt,32qt+32), shfl-combined) ----
  float dreg;
  {
    float dp = 0.f;
    const float4* ar = (const float4*)(Arow + 32*qt);
    const float4* cr = (const float4*)(c_s + 32*qt);
    #pragma unroll
    for (int k4 = 0; k4 < 8; k4++) {
      const float4 av = ar[k4], cv = cr[k4];
      dp += av.x*cv.x + av.y*cv.y + av.z*cv.z + av.w*cv.w;
    }
    const float d1 = dp + __shfl_xor(dp, 16, 64);
    dreg = d1 + __shfl_xor(d1, 32, 64);   // bitwise-identical in all 4 quarter lanes
  }

  // ---- V quarter: Vq[0..23] (48 floats) = V[j][48qt .. 48qt+47] ----
  v2f Vq[24];
  #pragma unroll
  for (int p = 0; p < 24; p++) Vq[p] = (v2f){0.f, 0.f};
  for (int m = 0; m < 32; m++) {
    const v4f a4 = *(const v4f*)&Arow[4*m];
    const float aks[4] = {a4.x, a4.y, a4.z, a4.w};
    #pragma unroll
    for (int kk = 0; kk < 4; kk++) {
      const v2f av = (v2f){aks[kk], aks[kk]};
      const float* w = &WT[(4*m + kk)*WT_LD + 48*qt];
      #pragma unroll
      for (int ch = 0; ch < 4; ch++) {
        const v4f w0 = *(const v4f*)&w[12*ch + 0];
        const v4f w1 = *(const v4f*)&w[12*ch + 4];
        const v4f w2 = *(const v4f*)&w[12*ch + 8];
        Vq[6*ch+0] = __builtin_elementwise_fma(av, (v2f){w0.x,w0.y}, Vq[6*ch+0]);
        Vq[6*ch+1] = __builtin_elementwise_fma(av, (v2f){w0.z,w0.w}, Vq[6*ch+1]);
        Vq[6*ch+2] = __builtin_elementwise_fma(av, (v2f){w1.x,w1.y}, Vq[6*ch+2]);
        Vq[6*ch+3] = __builtin_elementwise_fma(av, (v2f){w1.z,w1.w}, Vq[6*ch+3]);
        Vq[6*ch+4] = __builtin_elementwise_fma(av, (v2f){w2.x,w2.y}, Vq[6*ch+4]);
        Vq[6*ch+5] = __builtin_elementwise_fma(av, (v2f){w2.z,w2.w}, Vq[6*ch+5]);
      }
    }
  }

  float sreg = 0.f, preg = 0.f, Sacc = 0.f;
  bool cvg = false;

  // per iter/lane: 12 ds_read_b128 (4 addr/wave, 2-way bank alias = free),
  // 24 v_pk_fma, 2 shfl_xor, short chain. One barrier.
#define ITER(RD, WR, CHK, PH)                                                  \
  {                                                                            \
    const float* rp = (RD) + 48*qt;                                            \
    v2f q0=(v2f){0.f,0.f}, q1=(v2f){0.f,0.f};                                  \
    v2f q2=(v2f){0.f,0.f}, q3=(v2f){0.f,0.f};                                  \
    _Pragma("unroll")                                                          \
    for (int ch = 0; ch < 4; ch++) {                                           \
      const v4f s0 = *(const v4f*)&rp[12*ch + 0];                              \
      const v4f s1 = *(const v4f*)&rp[12*ch + 4];                              \
      const v4f s2 = *(const v4f*)&rp[12*ch + 8];                              \
      q0 = __builtin_elementwise_fma(Vq[6*ch+0], (v2f){s0.x,s0.y}, q0);        \
      q1 = __builtin_elementwise_fma(Vq[6*ch+1], (v2f){s0.z,s0.w}, q1);        \
      q2 = __builtin_elementwise_fma(Vq[6*ch+2], (v2f){s1.x,s1.y}, q2);        \
      q3 = __builtin_elementwise_fma(Vq[6*ch+3], (v2f){s1.z,s1.w}, q3);        \
      q0 = __builtin_elementwise_fma(Vq[6*ch+4], (v2f){s2.x,s2.y}, q0);        \
      q1 = __builtin_elementwise_fma(Vq[6*ch+5], (v2f){s2.z,s2.w}, q1);        \
    }                                                                          \
    q0 += q1; q2 += q3; q0 += q2;                                              \
    const float part = q0.x + q0.y;                                            \
    const float r1 = part + __shfl_xor(part, 16, 64);                          \
    const float r  = r1 + __shfl_xor(r1, 32, 64);                              \
    const float w  = r - dreg;                                                 \
    const float v  = fmaf(ALPHA_, w, preg);                                    \
    const float z  = __builtin_amdgcn_fmed3f(v, lreg, ureg);                   \
    const float sn = RHO_ * fmaf(2.0f, z, -v);                                 \
    const float pn = fmaf(-ALPHA_, z, v);                                      \
    if (wlane) (WR)[j] = sn;                                                   \
    if (CHK) { if (wlane && !(sn == sreg && pn == preg)) sflag[PH] = 1.f; }    \
    Sacc = fmaf(1.0f - ALPHA_, Sacc, ALPHA_ * sreg);                           \
    sreg = sn; preg = pn;                                                      \
    if ((CHK) && t == 0) sflag[(PH) ^ 1] = 0.f;                                \
    __syncthreads();                                                           \
    if (CHK) cvg = (sflag[PH] == 0.f);                                         \
  }

  #pragma unroll 1
  for (int it2 = 0; it2 < NITERS_/2; it2++) {
    ITER(sT0, sT1, false, 0)
    const bool chk = ((it2 & 3) == 3) && (it2 < NITERS_/2 - 40);
    const int ph = (it2 >> 2) & 1;
    ITER(sT1, sT0, chk, ph)
    if (cvg) break;   // bitwise fixed point: remaining iterations are identities
  }
#undef ITER
  if (cvg) Sacc = sreg;   // Sacc -> s* geometrically; |(-0.6)^80| ~ 2e-18

  // ---- epilogue: x = Wt^T Sacc - c  (= WtT rows . Sacc) ----
  if (wlane) sacc[j] = Sacc;
  __syncthreads();
  if (t < Nn) {
    const float* wr = &WT[t*WT_LD];
    v2f xa = (v2f){0.f,0.f}, xb = (v2f){0.f,0.f};
    #pragma unroll
    for (int j4 = 0; j4 < 48; j4++) {
      const v4f wv = *(const v4f*)&wr[4*j4];
      const v4f sv = *(const v4f*)&sacc[4*j4];
      xa = __builtin_elementwise_fma((v2f){wv.x,wv.y}, (v2f){sv.x,sv.y}, xa);
      xb = __builtin_elementwise_fma((v2f){wv.z,wv.w}, (v2f){sv.z,sv.w}, xb);
    }
    xa += xb;
    outg[(size_t)b*Nn + t] = xa.x + xa.y - c_s[t];
  }
}

extern "C" void kernel_launch(void* const* d_in, const int* in_sizes, int n_in,
                              void* d_out, int out_size, void* d_ws, size_t ws_size,
                              hipStream_t stream) {
  const float* P = (const float*)d_in[0];
  const float* q = (const float*)d_in[1];
  const float* A = (const float*)d_in[2];
  const float* l = (const float*)d_in[3];
  const float* u = (const float*)d_in[4];
  (void)in_sizes; (void)n_in; (void)out_size; (void)ws_size;
  float* wsWt = (float*)d_ws;                      // WtT: 256*128*192 floats = 25.2 MB
  float* wsC  = wsWt + (size_t)256*Mm*Nn;          // 256*128 floats
  precompute_kernel<<<256, 512, 0, stream>>>(P, q, A, wsWt, wsC);
  loop_kernel<<<256, 768, LOOP_LDS_FLOATS*4, stream>>>(A, l, u, wsWt, wsC, (float*)d_out);
}